// Round 8
// baseline (674.948 us; speedup 1.0000x reference)
//
#include <hip/hip_runtime.h>
#include <hip/hip_bf16.h>

// Problem constants
#define BB     2
#define SEQ    256
#define HH     2048
#define HKc    16
#define HVc    32
#define DKc    128
#define DVc    128
#define KC     4
#define KEYD   2048      // HKc*DKc
#define VALD   4096      // HVc*DVc
#define CONVD  8192      // 2*KEYD + VALD
#define MM     (BB*SEQ)  // 512
#define EPSf   1e-6f

typedef __attribute__((ext_vector_type(8))) short short8;
typedef __attribute__((ext_vector_type(4))) short short4v;
typedef __attribute__((ext_vector_type(4))) float floatx4;

__device__ __forceinline__ short f2bf(float f) {
  union { float f; unsigned u; } v; v.f = f;
  unsigned r = v.u + 0x7fffu + ((v.u >> 16) & 1u);   // RNE
  return (short)(r >> 16);
}

// ---------- MFMA bf16 GEMM: C[M,N] = A[M,K](fp32,lda) * B[K,N](fp32) -------
#define PADs 40
__global__ __launch_bounds__(256) void gemm_mfma(
    const float* __restrict__ A, const float* __restrict__ Bw,
    float* __restrict__ C, int M, int N, int Kd, int lda) {
  __shared__ short As[64 * PADs];
  __shared__ short Bs[128 * PADs];
  const int tid = threadIdx.x;
  const int wave = tid >> 6, lane = tid & 63;
  const int wm = (wave >> 1) * 32, wn = (wave & 1) * 64;
  const int bm = blockIdx.y * 64, bn = blockIdx.x * 128;
  floatx4 acc[2][4] = {};
  const int a_kq = tid & 7, a_m0 = tid >> 3;
  const int b_n = tid & 127, b_kh = (tid >> 7) * 8;
  const int fm = lane & 15, fq = (lane >> 4) * 8;
  for (int k0 = 0; k0 < Kd; k0 += 32) {
#pragma unroll
    for (int r = 0; r < 2; ++r) {
      int m = a_m0 + r * 32;
      const float4 f = *(const float4*)(A + (size_t)(bm + m) * lda + k0 + a_kq * 4);
      short4v sv; sv[0] = f2bf(f.x); sv[1] = f2bf(f.y); sv[2] = f2bf(f.z); sv[3] = f2bf(f.w);
      *(short4v*)&As[m * PADs + a_kq * 4] = sv;
    }
#pragma unroll
    for (int r = 0; r < 2; ++r) {
      int kk = b_kh + r * 16;
      short8 s;
#pragma unroll
      for (int j = 0; j < 8; ++j)
        s[j] = f2bf(Bw[(size_t)(k0 + kk + j) * N + bn + b_n]);
      *(short8*)&Bs[b_n * PADs + kk] = s;
    }
    __syncthreads();
    short8 af[2], bfr[4];
#pragma unroll
    for (int i = 0; i < 2; ++i)
      af[i] = *(const short8*)&As[(wm + i * 16 + fm) * PADs + fq];
#pragma unroll
    for (int j = 0; j < 4; ++j)
      bfr[j] = *(const short8*)&Bs[(wn + j * 16 + fm) * PADs + fq];
#pragma unroll
    for (int i = 0; i < 2; ++i)
#pragma unroll
      for (int j = 0; j < 4; ++j)
        acc[i][j] = __builtin_amdgcn_mfma_f32_16x16x32_bf16(af[i], bfr[j], acc[i][j], 0, 0, 0);
    __syncthreads();
  }
  const int cn = lane & 15, cr0 = (lane >> 4) * 4;
#pragma unroll
  for (int i = 0; i < 2; ++i)
#pragma unroll
    for (int j = 0; j < 4; ++j)
#pragma unroll
      for (int r = 0; r < 4; ++r)
        C[(size_t)(bm + wm + i * 16 + cr0 + r) * N + bn + wn + j * 16 + cn] = acc[i][j][r];
}

// -------- b/a projections fused with gating --------
__global__ __launch_bounds__(256) void proj_ab_kernel(
    const float* __restrict__ hs, const float* __restrict__ Wb,
    const float* __restrict__ Wa, const float* __restrict__ A_log,
    const float* __restrict__ dt_bias, float* __restrict__ g_out,
    float* __restrict__ beta_out) {
  __shared__ float xs[HH];
  __shared__ float part[4][64];
  const int row = blockIdx.x;
  const int t = threadIdx.x;
  for (int i = t; i < HH; i += 256) xs[i] = hs[(size_t)row * HH + i];
  __syncthreads();
  const int j = t & 63;
  const int kc = t >> 6;
  const float* W = (j < 32) ? Wb : Wa;
  const int jj = j & 31;
  float p = 0.f;
  const int k0 = kc * 512;
#pragma unroll 8
  for (int k = k0; k < k0 + 512; ++k) p += xs[k] * W[k * 32 + jj];
  part[kc][j] = p;
  __syncthreads();
  if (t < 64) {
    float dot = part[0][t] + part[1][t] + part[2][t] + part[3][t];
    if (t < 32) {
      beta_out[row * HVc + t] = 1.f / (1.f + expf(-dot));
    } else {
      int h = t - 32;
      float x = dot + dt_bias[h];
      float sp = (x > 20.f) ? x : log1pf(expf(x));
      g_out[row * HVc + h] = -expf(A_log[h]) * sp;
    }
  }
}

// -------- depthwise causal conv (K=4) + SiLU, parallel over s-chunks --------
#define CCH 16
__global__ __launch_bounds__(256) void conv_par_kernel(
    const float* __restrict__ mixed, const float* __restrict__ conv_state,
    const float* __restrict__ conv_w, const float* __restrict__ conv_b,
    float* __restrict__ cs) {
  const int c = blockIdx.x * 256 + threadIdx.x;   // channel
  const int s0 = blockIdx.y * CCH;
  const int b = blockIdx.z;
  const float4 w4 = *(const float4*)&conv_w[c * KC];
  const float bias = conv_b[c];
  float r0, r1, r2;
  if (s0 == 0) {
    size_t sb = (size_t)(b * CONVD + c) * (KC - 1);
    r0 = conv_state[sb + 0]; r1 = conv_state[sb + 1]; r2 = conv_state[sb + 2];
  } else {
    r0 = mixed[((size_t)(b * SEQ + s0 - 3)) * CONVD + c];
    r1 = mixed[((size_t)(b * SEQ + s0 - 2)) * CONVD + c];
    r2 = mixed[((size_t)(b * SEQ + s0 - 1)) * CONVD + c];
  }
#pragma unroll
  for (int s = s0; s < s0 + CCH; ++s) {
    size_t off = ((size_t)(b * SEQ + s)) * CONVD + c;
    float x = mixed[off];
    float acc = bias + r0 * w4.x + r1 * w4.y + r2 * w4.z + x * w4.w;
    cs[off] = acc / (1.f + expf(-acc));
    r0 = r1; r1 = r2; r2 = x;
  }
}

// -------- conv_state_out --------
__global__ __launch_bounds__(256) void conv_state_out_kernel(
    const float* __restrict__ mixed, float* __restrict__ out2) {
  int idx = blockIdx.x * 256 + threadIdx.x;
  int t = idx % (KC - 1);
  int c = (idx / (KC - 1)) & (CONVD - 1);
  int b = idx / ((KC - 1) * CONVD);
  out2[idx] = mixed[((size_t)(b * SEQ + SEQ - (KC - 1) + t)) * CONVD + c];
}

// -------- per-head l2norm of q (scaled) and k, in place on cs --------
__global__ __launch_bounds__(64) void l2norm_kernel(float* __restrict__ cs) {
  int bx = blockIdx.x;
  int which = bx & 1;
  int head = (bx >> 1) & 15;
  int row = bx >> 5;
  int lane = threadIdx.x;
  size_t base = (size_t)row * CONVD + (size_t)which * KEYD + head * DKc;
  float v0 = cs[base + lane];
  float v1 = cs[base + lane + 64];
  float ss = v0 * v0 + v1 * v1;
#pragma unroll
  for (int m = 1; m < 64; m <<= 1) ss += __shfl_xor(ss, m, 64);
  float rn = rsqrtf(ss + EPSf);
  if (!which) rn *= 0.08838834764831845f;
  cs[base + lane] = v0 * rn;
  cs[base + lane + 64] = v1 * rn;
}

// -------- delta-rule scan v4: 3-dot reformulation, depth-2 chunk pipeline ---
// o_t = eg*(q.S) + (q.k)*delta ; kv = eg*(k.S) ; S = eg*S + k*delta.
// Block (vg 0..7, h, b): 16 cols. lane = c16 + 16*kq. S[32]/lane.
#define SCH 16
#define LDCHUNK(CIDX)                                                        \
  {                                                                          \
    const int r1_ = r0g + (CIDX) * SCH;                                      \
    _Pragma("unroll")                                                        \
    for (int it = 0; it < 8; ++it) {                                         \
      int idx = it * 64 + lane, s_ = idx >> 5, d4 = idx & 31;                \
      const float* rp = cs + (size_t)(r1_ + s_) * CONVD;                     \
      kreg[it] = *(const float4*)(rp + kg + d4 * 4);                         \
      qreg[it] = *(const float4*)(rp + qg + d4 * 4);                         \
    }                                                                        \
    vreg = *(const float4*)(cs + (size_t)(r1_ + sv) * CONVD + vG + cv * 4);  \
    if (lane < SCH) egr = expf(g_in[(r1_ + lane) * HVc + h]);                \
    else if (lane < 2 * SCH) btr = beta_in[(r1_ + lane - SCH) * HVc + h];    \
  }
#define COMMIT(BUFI)                                                         \
  {                                                                          \
    _Pragma("unroll")                                                        \
    for (int it = 0; it < 8; ++it) {                                         \
      int idx = it * 64 + lane, s_ = idx >> 5, d4 = idx & 31;                \
      *(float4*)&kl[BUFI][s_ * 128 + d4 * 4] = kreg[it];                     \
      *(float4*)&ql[BUFI][s_ * 128 + d4 * 4] = qreg[it];                     \
    }                                                                        \
    *(float4*)&vl[BUFI][sv * 16 + cv * 4] = vreg;                            \
    if (lane < SCH) egl[BUFI][lane] = egr;                                   \
    else if (lane < 2 * SCH) btl[BUFI][lane - SCH] = btr;                    \
  }
__global__ __launch_bounds__(64) void scan_kernel(
    float* __restrict__ cs, const float* __restrict__ g_in,
    const float* __restrict__ beta_in, const float* __restrict__ rs0,
    const int* __restrict__ ctx, float* __restrict__ sfin) {
  const int vg = blockIdx.x, h = blockIdx.y, b = blockIdx.z;
  const int bh = b * HVc + h;
  const int lane = threadIdx.x;
  const int kq = lane >> 4;
  const int c16 = lane & 15;
  const int col = vg * 16 + c16;
  const int khead = h >> 1;
  __shared__ float kl[2][SCH * 128];
  __shared__ float ql[2][SCH * 128];
  __shared__ float vl[2][SCH * 16];
  __shared__ float egl[2][SCH];
  __shared__ float btl[2][SCH];
  float S[32];
#pragma unroll
  for (int i = 0; i < 32; ++i)
    S[i] = rs0[((size_t)bh * DKc + kq * 32 + i) * DVc + col];
  const int cl = ctx[b];
  const size_t qg = (size_t)khead * DKc;
  const size_t kg = KEYD + (size_t)khead * DKc;
  const size_t vG = 2 * KEYD + (size_t)h * DVc + vg * 16;
  const int r0g = b * SEQ;
  const int sv = lane >> 2, cv = lane & 3;
  float4 kreg[8], qreg[8], vreg;
  float egr = 0.f, btr = 0.f;
  const int NCH = SEQ / SCH;

  LDCHUNK(0); COMMIT(0);
  if (NCH > 1) LDCHUNK(1);

  // prologue: kcur + (u,w,r) for step 0 from buf 0
  float4 kcur[8];
  float u = 0.f, w = 0.f, r = 0.f;
#pragma unroll
  for (int j = 0; j < 8; ++j) {
    float4 kc = *(const float4*)&kl[0][kq * 32 + j * 4];
    float4 qc = *(const float4*)&ql[0][kq * 32 + j * 4];
    kcur[j] = kc;
    u += kc.x * S[4*j] + kc.y * S[4*j+1] + kc.z * S[4*j+2] + kc.w * S[4*j+3];
    w += qc.x * S[4*j] + qc.y * S[4*j+1] + qc.z * S[4*j+2] + qc.w * S[4*j+3];
    r += qc.x * kc.x + qc.y * kc.y + qc.z * kc.z + qc.w * kc.w;
  }
  u += __shfl_xor(u, 16, 64); u += __shfl_xor(u, 32, 64);
  w += __shfl_xor(w, 16, 64); w += __shfl_xor(w, 32, 64);
  r += __shfl_xor(r, 16, 64); r += __shfl_xor(r, 32, 64);

  for (int c = 0; c < NCH; ++c) {
    const int buf = c & 1;
    if (c + 1 < NCH) COMMIT(buf ^ 1);       // waits on chunk c+1 loads
    if (c + 2 < NCH) LDCHUNK(c + 2);        // issue chunk c+2 loads
    for (int s = 0; s < SCH; ++s) {
      const int sg = c * SCH + s;
      const float eg = egl[buf][s], bt = btl[buf][s];
      const float vv = vl[buf][s * 16 + c16];
      const bool act = (sg < cl);
      const float egm = act ? eg : 1.f;
      const float delta = act ? (vv - eg * u) * bt : 0.f;
      if (kq == 0) {
        const float o = eg * w + r * delta;
        cs[(size_t)(r0g + sg) * CONVD + vG + c16] = act ? o : 0.f;
      }
      // next step's k',q' (cross-chunk at s==SCH-1; clamp at very end)
      int s1 = s + 1, nbuf = buf;
      if (s1 == SCH) {
        if (c + 1 < NCH) { s1 = 0; nbuf = buf ^ 1; }
        else s1 = SCH - 1;
      }
      const float4* kn = (const float4*)&kl[nbuf][s1 * 128 + kq * 32];
      const float4* qn = (const float4*)&ql[nbuf][s1 * 128 + kq * 32];
      float u0 = 0.f, u1 = 0.f, w0 = 0.f, w1 = 0.f, rr0 = 0.f, rr1 = 0.f;
#pragma unroll
      for (int j = 0; j < 8; ++j) {
        const float4 kc = kcur[j];
        const float4 knj = kn[j], qnj = qn[j];
        float s0v = egm * S[4*j]   + kc.x * delta;
        float s1v = egm * S[4*j+1] + kc.y * delta;
        float s2v = egm * S[4*j+2] + kc.z * delta;
        float s3v = egm * S[4*j+3] + kc.w * delta;
        S[4*j] = s0v; S[4*j+1] = s1v; S[4*j+2] = s2v; S[4*j+3] = s3v;
        u0 += knj.x * s0v + knj.y * s1v;
        u1 += knj.z * s2v + knj.w * s3v;
        w0 += qnj.x * s0v + qnj.y * s1v;
        w1 += qnj.z * s2v + qnj.w * s3v;
        rr0 += qnj.x * knj.x + qnj.y * knj.y;
        rr1 += qnj.z * knj.z + qnj.w * knj.w;
        kcur[j] = knj;
      }
      float un = u0 + u1, wn = w0 + w1, rn = rr0 + rr1;
      un += __shfl_xor(un, 16, 64); un += __shfl_xor(un, 32, 64);
      wn += __shfl_xor(wn, 16, 64); wn += __shfl_xor(wn, 32, 64);
      rn += __shfl_xor(rn, 16, 64); rn += __shfl_xor(rn, 32, 64);
      u = un; w = wn; r = rn;
    }
  }
#pragma unroll
  for (int i = 0; i < 32; ++i)
    sfin[((size_t)bh * DKc + kq * 32 + i) * DVc + col] = S[i];
}

// -------- gated RMSNorm over DV + SiLU(z), in place on o (v-slot of cs) -----
__global__ __launch_bounds__(64) void normgate_kernel(
    float* __restrict__ cs, const float* __restrict__ zbuf,
    const float* __restrict__ norm_w) {
  int bx = blockIdx.x;
  int h = bx & 31;
  int row = bx >> 5;
  int lane = threadIdx.x;
  size_t base = (size_t)row * CONVD + 2 * KEYD + h * DVc;
  size_t zb = (size_t)row * VALD + h * DVc;
  float o0 = cs[base + lane];
  float o1 = cs[base + lane + 64];
  float ss = o0 * o0 + o1 * o1;
#pragma unroll
  for (int m = 1; m < 64; m <<= 1) ss += __shfl_xor(ss, m, 64);
  float rms = rsqrtf(ss * (1.f / 128.f) + EPSf);
  float z0 = zbuf[zb + lane];
  float z1 = zbuf[zb + lane + 64];
  cs[base + lane]      = o0 * rms * norm_w[lane]      * (z0 / (1.f + expf(-z0)));
  cs[base + lane + 64] = o1 * rms * norm_w[lane + 64] * (z1 / (1.f + expf(-z1)));
}

extern "C" void kernel_launch(void* const* d_in, const int* in_sizes, int n_in,
                              void* d_out, int out_size, void* d_ws, size_t ws_size,
                              hipStream_t stream) {
  const float* hs        = (const float*)d_in[0];
  const float* conv_st   = (const float*)d_in[1];
  const float* rec_st    = (const float*)d_in[2];
  const int*   ctx       = (const int*)d_in[3];
  const float* W_qkv     = (const float*)d_in[4];
  const float* W_z       = (const float*)d_in[5];
  const float* W_b       = (const float*)d_in[6];
  const float* W_a       = (const float*)d_in[7];
  const float* conv_w    = (const float*)d_in[8];
  const float* conv_b    = (const float*)d_in[9];
  const float* A_log     = (const float*)d_in[10];
  const float* dt_bias   = (const float*)d_in[11];
  const float* norm_w    = (const float*)d_in[12];
  const float* W_out     = (const float*)d_in[13];

  float* out0   = (float*)d_out;
  float* out_cv = out0 + (size_t)MM * HH;
  float* out_sf = out_cv + (size_t)BB * CONVD * (KC - 1);

  float* mixed = (float*)d_ws;
  float* cs    = mixed + (size_t)MM * CONVD;
  float* zbuf  = cs + (size_t)MM * CONVD;
  float* gbuf  = zbuf + (size_t)MM * VALD;
  float* betab = gbuf + (size_t)MM * HVc;

  gemm_mfma<<<dim3(CONVD / 128, MM / 64), 256, 0, stream>>>(hs, W_qkv, mixed, MM, CONVD, HH, HH);
  gemm_mfma<<<dim3(VALD / 128, MM / 64), 256, 0, stream>>>(hs, W_z, zbuf, MM, VALD, HH, HH);
  proj_ab_kernel<<<MM, 256, 0, stream>>>(hs, W_b, W_a, A_log, dt_bias, gbuf, betab);
  conv_par_kernel<<<dim3(CONVD / 256, SEQ / CCH, BB), 256, 0, stream>>>(
      mixed, conv_st, conv_w, conv_b, cs);
  conv_state_out_kernel<<<(BB * CONVD * (KC - 1)) / 256, 256, 0, stream>>>(mixed, out_cv);
  l2norm_kernel<<<MM * HKc * 2, 64, 0, stream>>>(cs);
  scan_kernel<<<dim3(8, HVc, BB), 64, 0, stream>>>(cs, gbuf, betab, rec_st, ctx, out_sf);
  normgate_kernel<<<MM * HVc, 64, 0, stream>>>(cs, zbuf, norm_w);
  gemm_mfma<<<dim3(HH / 128, MM / 64), 256, 0, stream>>>(
      cs + 2 * KEYD, W_out, out0, MM, HH, VALD, CONVD);
}